// Round 2
// baseline (272.170 us; speedup 1.0000x reference)
//
#include <hip/hip_runtime.h>
#include <math.h>

// Problem constants
// B=8, N=32, M=64, D=128, OUT=128, K=3, P=N*N=1024, r=512
#define EPS 1e-5f

// stats layout (floats) in ws[0..1023]:
//  [0..127]   sum_sc   [128..255] sq_sc
//  [256..319] sum1     [320..383] sq1
//  [384..447] sum2     [448..511] sq2
//  [512..543] sum3     [544..575] sq3

// ---------------------------------------------------------------------------
// K1: t_sc[b,o,n,d] = sum_m W_sc[o,m] x[b,n,m,d]
//     t_l1[b,c,n,d] = sum_m W_l1[c,m] x[b,n,m,d]
//     + per-channel sum/sumsq atomics.
// grid = 256 (b,n) * 4 channel-groups of 48; block 256.
__global__ __launch_bounds__(256) void k1_matmul_stats(
    const float* __restrict__ x, const float* __restrict__ Wsc,
    const float* __restrict__ Wl1, float* __restrict__ t_sc,
    float* __restrict__ t_l1, float* __restrict__ stats)
{
    int blk = blockIdx.x;
    int g  = blk & 3;          // channel group: channels [g*48, g*48+48)
    int bn = blk >> 2;         // 0..255
    int b = bn >> 5, n = bn & 31;
    __shared__ float s_x[64 * 128];
    __shared__ float s_w[48 * 64];
    int t = threadIdx.x;

    const float4* xg = (const float4*)(x + (size_t)bn * 8192);
    float4* sx4 = (float4*)s_x;
    for (int i = t; i < 2048; i += 256) sx4[i] = xg[i];

    for (int i = t; i < 48 * 16; i += 256) {    // 768 float4
        int r = i >> 4, j = i & 15;
        int cc = g * 48 + r;
        float4 w;
        if (cc < 128) w = ((const float4*)(Wsc + (size_t)cc * 64))[j];
        else          w = ((const float4*)(Wl1 + (size_t)(cc - 128) * 64))[j];
        ((float4*)(s_w + r * 64))[j] = w;
    }
    __syncthreads();

    int tx = t & 31, ty = t >> 5;   // tx: d-quad, ty: 0..7 (6 channels each)
    int d0 = tx * 4;
    float4 acc[6];
#pragma unroll
    for (int i = 0; i < 6; i++) acc[i] = make_float4(0.f, 0.f, 0.f, 0.f);

    for (int m = 0; m < 64; m++) {
        float4 xv = *(const float4*)(s_x + m * 128 + d0);
#pragma unroll
        for (int i = 0; i < 6; i++) {
            float w = s_w[(ty * 6 + i) * 64 + m];
            acc[i].x += w * xv.x; acc[i].y += w * xv.y;
            acc[i].z += w * xv.z; acc[i].w += w * xv.w;
        }
    }

#pragma unroll
    for (int i = 0; i < 6; i++) {
        int cc = g * 48 + ty * 6 + i;
        float4 v = acc[i];
        float* dst;
        if (cc < 128) dst = t_sc + (((size_t)(b * 128 + cc)) * 32 + n) * 128 + d0;
        else          dst = t_l1 + (((size_t)(b * 64 + (cc - 128))) * 32 + n) * 128 + d0;
        *(float4*)dst = v;
        float s = v.x + v.y + v.z + v.w;
        float q = v.x * v.x + v.y * v.y + v.z * v.z + v.w * v.w;
#pragma unroll
        for (int off = 16; off > 0; off >>= 1) {
            s += __shfl_down(s, off, 32);
            q += __shfl_down(q, off, 32);
        }
        if (tx == 0) {
            if (cc < 128) {
                atomicAdd(&stats[cc], s);
                atomicAdd(&stats[cc + 128], q);
            } else {
                atomicAdd(&stats[256 + (cc - 128)], s);
                atomicAdd(&stats[320 + (cc - 128)], q);
            }
        }
    }
}

// ---------------------------------------------------------------------------
// K2: per (b,m): y = bn1(t_l1); row sums S_i; dot/eq over pairs;
//     E[i*32+j] = (S_i + 2 S_j - eqsum_ij)/256; maskbits = (num>0); store y.
// grid 512, block 256.
__global__ __launch_bounds__(256) void k2_attn_prep(
    const float* __restrict__ t_l1, const float* __restrict__ g1,
    const float* __restrict__ b1, const float* __restrict__ stats,
    float* __restrict__ y_g, float* __restrict__ E,
    unsigned int* __restrict__ maskbits)
{
    int bm = blockIdx.x;
    int t  = threadIdx.x;
    __shared__ float y_s[32 * 132];
    __shared__ float S_s[32];
    __shared__ unsigned int m_s[32];
    int m = bm & 63;
    float mean = stats[256 + m] * (1.0f / 32768.0f);
    float var  = stats[320 + m] * (1.0f / 32768.0f) - mean * mean;
    float a = g1[m] * rsqrtf(var + EPS);
    float c = b1[m] - a * mean;

    if (t < 32) m_s[t] = 0u;
    const float4* src = (const float4*)(t_l1 + (size_t)bm * 4096);
    for (int i = t; i < 1024; i += 256) {
        float4 v = src[i];
        v.x = a * v.x + c; v.y = a * v.y + c; v.z = a * v.z + c; v.w = a * v.w + c;
        int row = i >> 5, col = (i & 31) * 4;
        *(float4*)(y_s + row * 132 + col) = v;
    }
    __syncthreads();

    {   // row sums
        int r = t >> 3, j = t & 7;
        float s = 0.f;
        const float* yr = y_s + r * 132 + j * 16;
#pragma unroll
        for (int dd = 0; dd < 16; dd++) s += yr[dd];
#pragma unroll
        for (int off = 4; off > 0; off >>= 1) s += __shfl_down(s, off, 8);
        if (j == 0) S_s[r] = s;
    }
    __syncthreads();

    int i = t >> 3, j0 = (t & 7) * 4;
    float dot[4] = {0.f, 0.f, 0.f, 0.f};
    float eqs[4] = {0.f, 0.f, 0.f, 0.f};
    const float* yi = y_s + i * 132;
    for (int dq = 0; dq < 32; dq++) {
        float4 a4 = *(const float4*)(yi + dq * 4);
#pragma unroll
        for (int q = 0; q < 4; q++) {
            float4 b4 = *(const float4*)(y_s + (j0 + q) * 132 + dq * 4);
            dot[q] += a4.x * b4.x + a4.y * b4.y + a4.z * b4.z + a4.w * b4.w;
            eqs[q] += (a4.x == b4.x ? b4.x : 0.f) + (a4.y == b4.y ? b4.y : 0.f)
                    + (a4.z == b4.z ? b4.z : 0.f) + (a4.w == b4.w ? b4.w : 0.f);
        }
    }
    float Si = S_s[i];
    unsigned int bits = 0u;
    float ev[4];
#pragma unroll
    for (int q = 0; q < 4; q++) {
        float Sj = S_s[j0 + q];
        float num = dot[q] - Si * Sj * (1.0f / 128.0f);
        if (num > 0.f) bits |= (1u << (j0 + q));
        ev[q] = (Si + 2.f * Sj - eqs[q]) * (1.0f / 256.0f);
    }
    atomicOr(&m_s[i], bits);
    *(float4*)(E + (size_t)bm * 1024 + i * 32 + j0) = make_float4(ev[0], ev[1], ev[2], ev[3]);
    __syncthreads();
    if (t < 32) maskbits[bm * 32 + t] = m_s[t];

    float4* yd = (float4*)(y_g + (size_t)bm * 4096);
    for (int idx = t; idx < 1024; idx += 256) {
        int row = idx >> 5, col = (idx & 31) * 4;
        yd[idx] = *(const float4*)(y_s + row * 132 + col);
    }
}

// ---------------------------------------------------------------------------
// K3: C[r, c] = epi( sum_k A[r,k] * Bm[c,k] ); 32x32 tiles, k-chunk 32.
// MODE 0: relu epilogue (FC1).  MODE 1: sigmoid epilogue (FC2).
template<int KDIM, int MODE>
__global__ __launch_bounds__(256) void k3_gemm(
    const float* __restrict__ A, const float* __restrict__ Bm,
    float* __restrict__ C, int NC)
{
    __shared__ float As[32 * 36];
    __shared__ float Bs[32 * 36];
    int t = threadIdx.x;
    int ct = blockIdx.x, rt = blockIdx.y;
    int rowA0 = rt * 32, colB0 = ct * 32;
    int tx = t & 15, ty = t >> 4;
    float acc[2][2] = {{0.f, 0.f}, {0.f, 0.f}};
    int lr = t >> 3, lc4 = (t & 7) * 4;

    for (int k0 = 0; k0 < KDIM; k0 += 32) {
        float4 av = *(const float4*)(A  + (size_t)(rowA0 + lr) * KDIM + k0 + lc4);
        float4 bv = *(const float4*)(Bm + (size_t)(colB0 + lr) * KDIM + k0 + lc4);
        __syncthreads();
        *(float4*)(As + lr * 36 + lc4) = av;
        *(float4*)(Bs + lr * 36 + lc4) = bv;
        __syncthreads();
#pragma unroll
        for (int kq = 0; kq < 8; kq++) {
            float4 a0 = *(const float4*)(As + ty * 36 + kq * 4);
            float4 a1 = *(const float4*)(As + (ty + 16) * 36 + kq * 4);
            float4 b0 = *(const float4*)(Bs + tx * 36 + kq * 4);
            float4 b1 = *(const float4*)(Bs + (tx + 16) * 36 + kq * 4);
            acc[0][0] += a0.x * b0.x + a0.y * b0.y + a0.z * b0.z + a0.w * b0.w;
            acc[0][1] += a0.x * b1.x + a0.y * b1.y + a0.z * b1.z + a0.w * b1.w;
            acc[1][0] += a1.x * b0.x + a1.y * b0.y + a1.z * b0.z + a1.w * b0.w;
            acc[1][1] += a1.x * b1.x + a1.y * b1.y + a1.z * b1.z + a1.w * b1.w;
        }
    }
#pragma unroll
    for (int ii = 0; ii < 2; ii++) {
        int r = rowA0 + ty + ii * 16;
#pragma unroll
        for (int jj = 0; jj < 2; jj++) {
            int cc = colB0 + tx + jj * 16;
            float v = acc[ii][jj];
            if (MODE == 0) v = fmaxf(v, 0.f);
            else           v = 1.0f / (1.0f + expf(-v));
            C[(size_t)r * NC + cc] = v;
        }
    }
}

// ---------------------------------------------------------------------------
// K4: per (b,m): att = softmax_j( mask ? e2 : -1e12 ); out = att @ y; stats2.
// grid 512, block 256.
__global__ __launch_bounds__(256) void k4_attn_apply(
    const float* __restrict__ E2, const unsigned int* __restrict__ maskbits,
    const float* __restrict__ y_g, float* __restrict__ att_out,
    float* __restrict__ stats)
{
    int bm = blockIdx.x;
    int t  = threadIdx.x;
    __shared__ float att_s[32 * 33];
    __shared__ float y_sh[32 * 128];
    __shared__ float redS[4], redQ[4];

    const float4* ysrc = (const float4*)(y_g + (size_t)bm * 4096);
    float4* yds = (float4*)y_sh;
    for (int i = t; i < 1024; i += 256) yds[i] = ysrc[i];

    {   // softmax: row r, 4 j's per thread
        int r = t >> 3, j0 = (t & 7) * 4;
        unsigned int mk = maskbits[bm * 32 + r];
        float4 e4 = *(const float4*)(E2 + (size_t)bm * 1024 + r * 32 + j0);
        float v0 = ((mk >> (j0 + 0)) & 1u) ? e4.x : -1e12f;
        float v1 = ((mk >> (j0 + 1)) & 1u) ? e4.y : -1e12f;
        float v2 = ((mk >> (j0 + 2)) & 1u) ? e4.z : -1e12f;
        float v3 = ((mk >> (j0 + 3)) & 1u) ? e4.w : -1e12f;
        float mx = fmaxf(fmaxf(v0, v1), fmaxf(v2, v3));
#pragma unroll
        for (int off = 1; off < 8; off <<= 1) mx = fmaxf(mx, __shfl_xor(mx, off, 8));
        float e0 = __expf(v0 - mx), e1 = __expf(v1 - mx);
        float e2 = __expf(v2 - mx), e3 = __expf(v3 - mx);
        float s = e0 + e1 + e2 + e3;
#pragma unroll
        for (int off = 1; off < 8; off <<= 1) s += __shfl_xor(s, off, 8);
        float inv = 1.0f / s;
        att_s[r * 33 + j0 + 0] = e0 * inv;
        att_s[r * 33 + j0 + 1] = e1 * inv;
        att_s[r * 33 + j0 + 2] = e2 * inv;
        att_s[r * 33 + j0 + 3] = e3 * inv;
    }
    __syncthreads();

    int tx = t & 31, ty = t >> 5;
    int dq = tx * 4;
    float ssum = 0.f, sq = 0.f;
#pragma unroll
    for (int ii = 0; ii < 4; ii++) {
        int i = ty * 4 + ii;
        float4 acc = make_float4(0.f, 0.f, 0.f, 0.f);
        for (int j = 0; j < 32; j++) {
            float aw = att_s[i * 33 + j];
            float4 yv = *(const float4*)(y_sh + j * 128 + dq);
            acc.x += aw * yv.x; acc.y += aw * yv.y;
            acc.z += aw * yv.z; acc.w += aw * yv.w;
        }
        *(float4*)(att_out + (size_t)bm * 4096 + i * 128 + dq) = acc;
        ssum += acc.x + acc.y + acc.z + acc.w;
        sq   += acc.x * acc.x + acc.y * acc.y + acc.z * acc.z + acc.w * acc.w;
    }
#pragma unroll
    for (int off = 32; off > 0; off >>= 1) {
        ssum += __shfl_down(ssum, off, 64);
        sq   += __shfl_down(sq, off, 64);
    }
    int wave = t >> 6, lane = t & 63;
    if (lane == 0) { redS[wave] = ssum; redQ[wave] = sq; }
    __syncthreads();
    if (t == 0) {
        float S = redS[0] + redS[1] + redS[2] + redS[3];
        float Q = redQ[0] + redQ[1] + redQ[2] + redQ[3];
        int m = bm & 63;
        atomicAdd(&stats[384 + m], S);
        atomicAdd(&stats[448 + m], Q);
    }
}

// ---------------------------------------------------------------------------
// K5: per (b,n): z = relu(bn2(att_out)) over (m,d) plane; 3x3 depthwise conv
//     (zero pad), write raw conv; stats3 per channel n.
// grid 256, block 256.
__global__ __launch_bounds__(256) void k5_conv(
    const float* __restrict__ att_out, const float* __restrict__ Wdw,
    const float* __restrict__ g2, const float* __restrict__ b2,
    float* __restrict__ stats, float* __restrict__ v_g)
{
    int bn = blockIdx.x;
    int b = bn >> 5, n = bn & 31;
    int t = threadIdx.x;
    __shared__ float z_s[66 * 130];
    __shared__ float a2_s[64], c2_s[64];
    __shared__ float redS[4], redQ[4];

    if (t < 64) {
        float mean = stats[384 + t] * (1.0f / 32768.0f);
        float var  = stats[448 + t] * (1.0f / 32768.0f) - mean * mean;
        float a = g2[t] * rsqrtf(var + EPS);
        a2_s[t] = a; c2_s[t] = b2[t] - a * mean;
    }
    for (int i = t; i < 66 * 130; i += 256) z_s[i] = 0.f;
    __syncthreads();

    for (int i = t; i < 2048; i += 256) {
        int m = i >> 5, c4 = (i & 31) * 4;
        float4 vv = *(const float4*)(att_out + (((size_t)(b * 64 + m)) * 32 + n) * 128 + c4);
        float a = a2_s[m], c = c2_s[m];
        float* dst = z_s + (m + 1) * 130 + c4 + 1;
        dst[0] = fmaxf(a * vv.x + c, 0.f);
        dst[1] = fmaxf(a * vv.y + c, 0.f);
        dst[2] = fmaxf(a * vv.z + c, 0.f);
        dst[3] = fmaxf(a * vv.w + c, 0.f);
    }
    float w[9];
#pragma unroll
    for (int i = 0; i < 9; i++) w[i] = Wdw[n * 9 + i];
    __syncthreads();

    int tx = t & 31, ty = t >> 5;
    int d0 = tx * 4;
    float ssum = 0.f, sq = 0.f;
#pragma unroll
    for (int rr = 0; rr < 8; rr++) {
        int h = ty * 8 + rr;
        float o0 = 0.f, o1 = 0.f, o2 = 0.f, o3 = 0.f;
#pragma unroll
        for (int dh = 0; dh < 3; dh++) {
            const float* zr = z_s + (h + dh) * 130 + d0;
#pragma unroll
            for (int dw = 0; dw < 3; dw++) {
                float wv = w[dh * 3 + dw];
                o0 += wv * zr[dw + 0];
                o1 += wv * zr[dw + 1];
                o2 += wv * zr[dw + 2];
                o3 += wv * zr[dw + 3];
            }
        }
        *(float4*)(v_g + ((size_t)bn * 64 + h) * 128 + d0) = make_float4(o0, o1, o2, o3);
        ssum += o0 + o1 + o2 + o3;
        sq   += o0 * o0 + o1 * o1 + o2 * o2 + o3 * o3;
    }
#pragma unroll
    for (int off = 32; off > 0; off >>= 1) {
        ssum += __shfl_down(ssum, off, 64);
        sq   += __shfl_down(sq, off, 64);
    }
    int wave = t >> 6, lane = t & 63;
    if (lane == 0) { redS[wave] = ssum; redQ[wave] = sq; }
    __syncthreads();
    if (t == 0) {
        atomicAdd(&stats[512 + n], redS[0] + redS[1] + redS[2] + redS[3]);
        atomicAdd(&stats[544 + n], redQ[0] + redQ[1] + redQ[2] + redQ[3]);
    }
}

// ---------------------------------------------------------------------------
// K6: per (b,n,o-half): out[b,n,o,d] = sum_m Wl3[o,m]*relu(bn3(v[b,n,m,d]))
//                                      + bn_sc(t_sc[b,o,n,d])
// grid 512, block 256.
__global__ __launch_bounds__(256) void k6_final(
    const float* __restrict__ v_g, const float* __restrict__ t_sc,
    const float* __restrict__ Wl3, const float* __restrict__ g3,
    const float* __restrict__ b3, const float* __restrict__ gsc,
    const float* __restrict__ bsc, const float* __restrict__ stats,
    float* __restrict__ outp)
{
    int blk = blockIdx.x;
    int half = blk & 1;
    int bn = blk >> 1;
    int b = bn >> 5, n = bn & 31;
    int t = threadIdx.x;
    __shared__ float w_s[64 * 128];
    __shared__ float wl3_s[64 * 64];

    int nn = n;
    float mean3 = stats[512 + nn] * (1.0f / 65536.0f);
    float var3  = stats[544 + nn] * (1.0f / 65536.0f) - mean3 * mean3;
    float a3 = g3[nn] * rsqrtf(var3 + EPS);
    float c3 = b3[nn] - a3 * mean3;

    const float4* vsrc = (const float4*)(v_g + (size_t)bn * 8192);
    for (int i = t; i < 2048; i += 256) {
        float4 vv = vsrc[i];
        float4 r;
        r.x = fmaxf(a3 * vv.x + c3, 0.f);
        r.y = fmaxf(a3 * vv.y + c3, 0.f);
        r.z = fmaxf(a3 * vv.z + c3, 0.f);
        r.w = fmaxf(a3 * vv.w + c3, 0.f);
        ((float4*)w_s)[i] = r;
    }
    const float4* wsrc = (const float4*)(Wl3 + (size_t)half * 64 * 64);
    for (int i = t; i < 1024; i += 256) ((float4*)wl3_s)[i] = wsrc[i];
    __syncthreads();

    int tx = t & 31, ty = t >> 5;
    int dq = tx * 4;
    float4 acc[8];
#pragma unroll
    for (int oo = 0; oo < 8; oo++) {
        int o = half * 64 + ty * 8 + oo;
        float msc = stats[o] * (1.0f / 32768.0f);
        float vsc = stats[128 + o] * (1.0f / 32768.0f) - msc * msc;
        float asc = gsc[o] * rsqrtf(vsc + EPS);
        float csc = bsc[o] - asc * msc;
        float4 ts = *(const float4*)(t_sc + (((size_t)(b * 128 + o)) * 32 + n) * 128 + dq);
        acc[oo].x = asc * ts.x + csc;
        acc[oo].y = asc * ts.y + csc;
        acc[oo].z = asc * ts.z + csc;
        acc[oo].w = asc * ts.w + csc;
    }
    for (int m = 0; m < 64; m++) {
        float4 wv = *(const float4*)(w_s + m * 128 + dq);
#pragma unroll
        for (int oo = 0; oo < 8; oo++) {
            float wl = wl3_s[(ty * 8 + oo) * 64 + m];
            acc[oo].x += wl * wv.x; acc[oo].y += wl * wv.y;
            acc[oo].z += wl * wv.z; acc[oo].w += wl * wv.w;
        }
    }
#pragma unroll
    for (int oo = 0; oo < 8; oo++) {
        int o = half * 64 + ty * 8 + oo;
        *(float4*)(outp + (((size_t)(b * 32 + n)) * 128 + o) * 128 + dq) = acc[oo];
    }
}

// ---------------------------------------------------------------------------
extern "C" void kernel_launch(void* const* d_in, const int* in_sizes, int n_in,
                              void* d_out, int out_size, void* d_ws, size_t ws_size,
                              hipStream_t stream)
{
    const float* x    = (const float*)d_in[0];
    const float* Wsc  = (const float*)d_in[1];
    const float* gsc  = (const float*)d_in[2];
    const float* bsc  = (const float*)d_in[3];
    const float* Wl1  = (const float*)d_in[4];
    const float* g1   = (const float*)d_in[5];
    const float* b1   = (const float*)d_in[6];
    const float* Wfc1 = (const float*)d_in[7];
    const float* Wfc2 = (const float*)d_in[8];
    const float* g2   = (const float*)d_in[9];
    const float* b2   = (const float*)d_in[10];
    const float* Wdw  = (const float*)d_in[11];
    const float* g3   = (const float*)d_in[12];
    const float* b3   = (const float*)d_in[13];
    const float* Wl3  = (const float*)d_in[14];
    float* outp = (float*)d_out;

    float* ws = (float*)d_ws;
    float* stats = ws;                          // 1024
    float* t_sc  = ws + 1024;                   // 4194304
    float* t_l1  = t_sc + 4194304;              // 2097152 (reused as att_out)
    float* y_g   = t_l1 + 2097152;              // 2097152 (reused as conv out)
    float* E     = y_g + 2097152;               // 524288
    float* H     = E + 524288;                  // 262144
    float* E2    = H + 262144;                  // 524288
    unsigned int* maskb = (unsigned int*)(E2 + 524288);  // 16384 u32

    (void)hipMemsetAsync(stats, 0, 1024 * sizeof(float), stream);

    k1_matmul_stats<<<1024, 256, 0, stream>>>(x, Wsc, Wl1, t_sc, t_l1, stats);
    k2_attn_prep<<<512, 256, 0, stream>>>(t_l1, g1, b1, stats, y_g, E, maskb);
    k3_gemm<1024, 0><<<dim3(16, 16), 256, 0, stream>>>(E, Wfc1, H, 512);
    k3_gemm<512, 1><<<dim3(32, 16), 256, 0, stream>>>(H, Wfc2, E2, 1024);
    k4_attn_apply<<<512, 256, 0, stream>>>(E2, maskb, y_g, t_l1, stats);
    k5_conv<<<256, 256, 0, stream>>>(t_l1, Wdw, g2, b2, stats, y_g);
    k6_final<<<512, 256, 0, stream>>>(y_g, t_sc, Wl3, g3, b3, gsc, bsc, stats, outp);
}

// Round 3
// 210.455 us; speedup vs baseline: 1.2932x; 1.2932x over previous
//
#include <hip/hip_runtime.h>
#include <math.h>

// B=8, N=32, M=64, D=128, OUT=128, K=3, P=N*N=1024, r=512
#define EPS 1e-5f

// stats layout (floats) in ws[0..1023]:
//  [0..127]   sum_sc   [128..255] sq_sc
//  [256..319] sum1     [320..383] sq1
//  [384..447] sum2     [448..511] sq2
//  [512..543] sum3     [544..575] sq3

__device__ __forceinline__ void fma4(float4& a, float s, const float4& v) {
    a.x += s * v.x; a.y += s * v.y; a.z += s * v.z; a.w += s * v.w;
}

// ---------------------------------------------------------------------------
// K1 v2: t_sc[b,o,n,d] = sum_m W_sc[o,m] x[b,n,m,d]; t_l1 likewise for W_l1.
// grid (3, 256): x = ch-group of 64 concat channels, y = (b,n). block 256.
// Register tile: 4 ch x 8 d per lane; weights transposed in LDS ([m][cc]).
__global__ __launch_bounds__(256) void k1_matmul_stats(
    const float* __restrict__ x, const float* __restrict__ Wsc,
    const float* __restrict__ Wl1, float* __restrict__ t_sc,
    float* __restrict__ t_l1, float* __restrict__ stats)
{
    int g  = blockIdx.x;       // 0..2
    int bn = blockIdx.y;       // 0..255
    int b = bn >> 5, n = bn & 31;
    __shared__ __align__(16) float s_x[64 * 128];   // [m][d]
    __shared__ __align__(16) float s_wT[64 * 68];   // [m][cc_local], pad 68
    int t = threadIdx.x;

    const float4* xg = (const float4*)(x + (size_t)bn * 8192);
    for (int i = t; i < 2048; i += 256) ((float4*)s_x)[i] = xg[i];

    // weights: block's 64 concat channels [g*64, g*64+64). Region uniform per g.
    const float* wbase = (g < 2) ? (Wsc + (size_t)g * 64 * 64) : Wl1;
    for (int i = t; i < 1024; i += 256) {
        int m = i >> 4, rq = (i & 15) * 4;
        float4 wv;
        wv.x = wbase[(size_t)(rq + 0) * 64 + m];
        wv.y = wbase[(size_t)(rq + 1) * 64 + m];
        wv.z = wbase[(size_t)(rq + 2) * 64 + m];
        wv.w = wbase[(size_t)(rq + 3) * 64 + m];
        *(float4*)(s_wT + m * 68 + rq) = wv;
    }
    __syncthreads();

    int wv = t >> 6, lane = t & 63;
    int dl = lane & 15;        // d-oct index
    int g4 = lane >> 4;        // 0..3
    int d0 = dl * 8;
    int c0 = wv * 16 + g4 * 4; // local cc base, 4 channels

    float4 acc[4][2];
#pragma unroll
    for (int i = 0; i < 4; i++) { acc[i][0] = make_float4(0,0,0,0); acc[i][1] = make_float4(0,0,0,0); }

    for (int m = 0; m < 64; m += 2) {
        float4 x00 = *(const float4*)(s_x + m * 128 + d0);
        float4 x01 = *(const float4*)(s_x + m * 128 + d0 + 4);
        float4 x10 = *(const float4*)(s_x + (m + 1) * 128 + d0);
        float4 x11 = *(const float4*)(s_x + (m + 1) * 128 + d0 + 4);
        float4 w0 = *(const float4*)(s_wT + m * 68 + c0);
        float4 w1 = *(const float4*)(s_wT + (m + 1) * 68 + c0);
        fma4(acc[0][0], w0.x, x00); fma4(acc[0][1], w0.x, x01);
        fma4(acc[1][0], w0.y, x00); fma4(acc[1][1], w0.y, x01);
        fma4(acc[2][0], w0.z, x00); fma4(acc[2][1], w0.z, x01);
        fma4(acc[3][0], w0.w, x00); fma4(acc[3][1], w0.w, x01);
        fma4(acc[0][0], w1.x, x10); fma4(acc[0][1], w1.x, x11);
        fma4(acc[1][0], w1.y, x10); fma4(acc[1][1], w1.y, x11);
        fma4(acc[2][0], w1.z, x10); fma4(acc[2][1], w1.z, x11);
        fma4(acc[3][0], w1.w, x10); fma4(acc[3][1], w1.w, x11);
    }

#pragma unroll
    for (int i = 0; i < 4; i++) {
        int cc = g * 64 + c0 + i;
        float4 v0 = acc[i][0], v1 = acc[i][1];
        float* dst;
        if (cc < 128) dst = t_sc + (((size_t)(b * 128 + cc)) * 32 + n) * 128 + d0;
        else          dst = t_l1 + (((size_t)(b * 64 + (cc - 128))) * 32 + n) * 128 + d0;
        *(float4*)dst = v0;
        *(float4*)(dst + 4) = v1;
        float s = v0.x + v0.y + v0.z + v0.w + v1.x + v1.y + v1.z + v1.w;
        float q = v0.x*v0.x + v0.y*v0.y + v0.z*v0.z + v0.w*v0.w
                + v1.x*v1.x + v1.y*v1.y + v1.z*v1.z + v1.w*v1.w;
#pragma unroll
        for (int off = 8; off > 0; off >>= 1) {
            s += __shfl_down(s, off, 16);
            q += __shfl_down(q, off, 16);
        }
        if (dl == 0) {
            if (cc < 128) {
                atomicAdd(&stats[cc], s);
                atomicAdd(&stats[cc + 128], q);
            } else {
                atomicAdd(&stats[256 + (cc - 128)], s);
                atomicAdd(&stats[320 + (cc - 128)], q);
            }
        }
    }
}

// ---------------------------------------------------------------------------
// K2: per (b,m): y = bn1(t_l1); row sums S_i; dot/eq over pairs;
//     E[i*32+j] = (S_i + 2 S_j - eqsum_ij)/256; maskbits = (num>0); store y.
__global__ __launch_bounds__(256) void k2_attn_prep(
    const float* __restrict__ t_l1, const float* __restrict__ g1,
    const float* __restrict__ b1, const float* __restrict__ stats,
    float* __restrict__ y_g, float* __restrict__ E,
    unsigned int* __restrict__ maskbits)
{
    int bm = blockIdx.x;
    int t  = threadIdx.x;
    __shared__ __align__(16) float y_s[32 * 132];
    __shared__ float S_s[32];
    __shared__ unsigned int m_s[32];
    int m = bm & 63;
    float mean = stats[256 + m] * (1.0f / 32768.0f);
    float var  = stats[320 + m] * (1.0f / 32768.0f) - mean * mean;
    float a = g1[m] * rsqrtf(var + EPS);
    float c = b1[m] - a * mean;

    if (t < 32) m_s[t] = 0u;
    const float4* src = (const float4*)(t_l1 + (size_t)bm * 4096);
    for (int i = t; i < 1024; i += 256) {
        float4 v = src[i];
        v.x = a * v.x + c; v.y = a * v.y + c; v.z = a * v.z + c; v.w = a * v.w + c;
        int row = i >> 5, col = (i & 31) * 4;
        *(float4*)(y_s + row * 132 + col) = v;
    }
    __syncthreads();

    {   // row sums
        int r = t >> 3, j = t & 7;
        float s = 0.f;
        const float* yr = y_s + r * 132 + j * 16;
#pragma unroll
        for (int dd = 0; dd < 16; dd++) s += yr[dd];
#pragma unroll
        for (int off = 4; off > 0; off >>= 1) s += __shfl_down(s, off, 8);
        if (j == 0) S_s[r] = s;
    }
    __syncthreads();

    int i = t >> 3, j0 = (t & 7) * 4;
    float dot[4] = {0.f, 0.f, 0.f, 0.f};
    float eqs[4] = {0.f, 0.f, 0.f, 0.f};
    const float* yi = y_s + i * 132;
    for (int dq = 0; dq < 32; dq++) {
        float4 a4 = *(const float4*)(yi + dq * 4);
#pragma unroll
        for (int q = 0; q < 4; q++) {
            float4 b4 = *(const float4*)(y_s + (j0 + q) * 132 + dq * 4);
            dot[q] += a4.x * b4.x + a4.y * b4.y + a4.z * b4.z + a4.w * b4.w;
            eqs[q] += (a4.x == b4.x ? b4.x : 0.f) + (a4.y == b4.y ? b4.y : 0.f)
                    + (a4.z == b4.z ? b4.z : 0.f) + (a4.w == b4.w ? b4.w : 0.f);
        }
    }
    float Si = S_s[i];
    unsigned int bits = 0u;
    float ev[4];
#pragma unroll
    for (int q = 0; q < 4; q++) {
        float Sj = S_s[j0 + q];
        float num = dot[q] - Si * Sj * (1.0f / 128.0f);
        if (num > 0.f) bits |= (1u << (j0 + q));
        ev[q] = (Si + 2.f * Sj - eqs[q]) * (1.0f / 256.0f);
    }
    atomicOr(&m_s[i], bits);
    *(float4*)(E + (size_t)bm * 1024 + i * 32 + j0) = make_float4(ev[0], ev[1], ev[2], ev[3]);
    __syncthreads();
    if (t < 32) maskbits[bm * 32 + t] = m_s[t];

    float4* yd = (float4*)(y_g + (size_t)bm * 4096);
    for (int idx = t; idx < 1024; idx += 256) {
        int row = idx >> 5, col = (idx & 31) * 4;
        yd[idx] = *(const float4*)(y_s + row * 132 + col);
    }
}

// ---------------------------------------------------------------------------
// K3 v2: C[r,c] = epi( sum_k A[r,k] * Bm[c,k] ). 32x32 tile per block,
// in-block split-K: 4 waves, each owns K/4 via wave-private LDS slabs of 32k
// (no in-loop barriers). 4x4 register tile per lane. Reduce via LDS.
// MODE 0: relu (FC1).  MODE 1: sigmoid (FC2).
template<int KDIM, int MODE>
__global__ __launch_bounds__(256) void k3_gemm(
    const float* __restrict__ A, const float* __restrict__ Bm,
    float* __restrict__ C, int NC)
{
    __shared__ __align__(16) float lds[4 * 2304];   // per wave: As 32x36, Bs 32x36
    int t = threadIdx.x;
    int w = t >> 6, l = t & 63;
    int ct = blockIdx.x, rt = blockIdx.y;
    int row0 = rt * 32, col0 = ct * 32;
    float* As = lds + w * 2304;
    float* Bs = As + 1152;
    int rg = l >> 3;           // 0..7 : rows rg*4.., also staging row group
    int cg = l & 7;            // 0..7 : cols cg*4..
    int kq = (l & 7) * 4;      // staging k-offset within slab
    constexpr int SLABS = KDIM / 128;

    float4 acc[4];
#pragma unroll
    for (int ii = 0; ii < 4; ii++) acc[ii] = make_float4(0,0,0,0);

    float4 av[4], bv[4], av2[4], bv2[4];
    int k0 = w * 32;
#pragma unroll
    for (int rr = 0; rr < 4; rr++) {
        int r = rg + rr * 8;
        av[rr] = *(const float4*)(A  + (size_t)(row0 + r) * KDIM + k0 + kq);
        bv[rr] = *(const float4*)(Bm + (size_t)(col0 + r) * KDIM + k0 + kq);
    }

    for (int s = 0; s < SLABS; s++) {
#pragma unroll
        for (int rr = 0; rr < 4; rr++) {
            int r = rg + rr * 8;
            As[(kq + 0) * 36 + r] = av[rr].x; As[(kq + 1) * 36 + r] = av[rr].y;
            As[(kq + 2) * 36 + r] = av[rr].z; As[(kq + 3) * 36 + r] = av[rr].w;
            Bs[(kq + 0) * 36 + r] = bv[rr].x; Bs[(kq + 1) * 36 + r] = bv[rr].y;
            Bs[(kq + 2) * 36 + r] = bv[rr].z; Bs[(kq + 3) * 36 + r] = bv[rr].w;
        }
        if (s + 1 < SLABS) {
            int kn = (4 * (s + 1) + w) * 32;
#pragma unroll
            for (int rr = 0; rr < 4; rr++) {
                int r = rg + rr * 8;
                av2[rr] = *(const float4*)(A  + (size_t)(row0 + r) * KDIM + kn + kq);
                bv2[rr] = *(const float4*)(Bm + (size_t)(col0 + r) * KDIM + kn + kq);
            }
        }
#pragma unroll
        for (int k = 0; k < 32; k++) {
            float4 a = *(const float4*)(As + k * 36 + rg * 4);
            float4 b = *(const float4*)(Bs + k * 36 + cg * 4);
            fma4(acc[0], a.x, b);
            fma4(acc[1], a.y, b);
            fma4(acc[2], a.z, b);
            fma4(acc[3], a.w, b);
        }
#pragma unroll
        for (int rr = 0; rr < 4; rr++) { av[rr] = av2[rr]; bv[rr] = bv2[rr]; }
    }

    __syncthreads();
    float* red = lds;          // 4 x 1024 overlay
#pragma unroll
    for (int ii = 0; ii < 4; ii++)
        *(float4*)(red + w * 1024 + (rg * 4 + ii) * 32 + cg * 4) = acc[ii];
    __syncthreads();

    int r = t >> 3, c4 = (t & 7) * 4;
    float4 s0 = *(const float4*)(red + r * 32 + c4);
    float4 s1 = *(const float4*)(red + 1024 + r * 32 + c4);
    float4 s2 = *(const float4*)(red + 2048 + r * 32 + c4);
    float4 s3 = *(const float4*)(red + 3072 + r * 32 + c4);
    float4 v;
    v.x = s0.x + s1.x + s2.x + s3.x;
    v.y = s0.y + s1.y + s2.y + s3.y;
    v.z = s0.z + s1.z + s2.z + s3.z;
    v.w = s0.w + s1.w + s2.w + s3.w;
    if (MODE == 0) {
        v.x = fmaxf(v.x, 0.f); v.y = fmaxf(v.y, 0.f);
        v.z = fmaxf(v.z, 0.f); v.w = fmaxf(v.w, 0.f);
    } else {
        v.x = 1.0f / (1.0f + expf(-v.x)); v.y = 1.0f / (1.0f + expf(-v.y));
        v.z = 1.0f / (1.0f + expf(-v.z)); v.w = 1.0f / (1.0f + expf(-v.w));
    }
    *(float4*)(C + (size_t)(row0 + r) * NC + col0 + c4) = v;
}

// ---------------------------------------------------------------------------
// K4: per (b,m): att = softmax_j( mask ? e2 : -1e12 ); out = att @ y; stats2.
__global__ __launch_bounds__(256) void k4_attn_apply(
    const float* __restrict__ E2, const unsigned int* __restrict__ maskbits,
    const float* __restrict__ y_g, float* __restrict__ att_out,
    float* __restrict__ stats)
{
    int bm = blockIdx.x;
    int t  = threadIdx.x;
    __shared__ __align__(16) float att_s[32 * 33];
    __shared__ __align__(16) float y_sh[32 * 128];
    __shared__ float redS[4], redQ[4];

    const float4* ysrc = (const float4*)(y_g + (size_t)bm * 4096);
    float4* yds = (float4*)y_sh;
    for (int i = t; i < 1024; i += 256) yds[i] = ysrc[i];

    {
        int r = t >> 3, j0 = (t & 7) * 4;
        unsigned int mk = maskbits[bm * 32 + r];
        float4 e4 = *(const float4*)(E2 + (size_t)bm * 1024 + r * 32 + j0);
        float v0 = ((mk >> (j0 + 0)) & 1u) ? e4.x : -1e12f;
        float v1 = ((mk >> (j0 + 1)) & 1u) ? e4.y : -1e12f;
        float v2 = ((mk >> (j0 + 2)) & 1u) ? e4.z : -1e12f;
        float v3 = ((mk >> (j0 + 3)) & 1u) ? e4.w : -1e12f;
        float mx = fmaxf(fmaxf(v0, v1), fmaxf(v2, v3));
#pragma unroll
        for (int off = 1; off < 8; off <<= 1) mx = fmaxf(mx, __shfl_xor(mx, off, 8));
        float e0 = __expf(v0 - mx), e1 = __expf(v1 - mx);
        float e2 = __expf(v2 - mx), e3 = __expf(v3 - mx);
        float s = e0 + e1 + e2 + e3;
#pragma unroll
        for (int off = 1; off < 8; off <<= 1) s += __shfl_xor(s, off, 8);
        float inv = 1.0f / s;
        att_s[r * 33 + j0 + 0] = e0 * inv;
        att_s[r * 33 + j0 + 1] = e1 * inv;
        att_s[r * 33 + j0 + 2] = e2 * inv;
        att_s[r * 33 + j0 + 3] = e3 * inv;
    }
    __syncthreads();

    int tx = t & 31, ty = t >> 5;
    int dq = tx * 4;
    float ssum = 0.f, sq = 0.f;
#pragma unroll
    for (int ii = 0; ii < 4; ii++) {
        int i = ty * 4 + ii;
        float4 acc = make_float4(0.f, 0.f, 0.f, 0.f);
        for (int j = 0; j < 32; j++) {
            float aw = att_s[i * 33 + j];
            float4 yv = *(const float4*)(y_sh + j * 128 + dq);
            acc.x += aw * yv.x; acc.y += aw * yv.y;
            acc.z += aw * yv.z; acc.w += aw * yv.w;
        }
        *(float4*)(att_out + (size_t)bm * 4096 + i * 128 + dq) = acc;
        ssum += acc.x + acc.y + acc.z + acc.w;
        sq   += acc.x * acc.x + acc.y * acc.y + acc.z * acc.z + acc.w * acc.w;
    }
#pragma unroll
    for (int off = 32; off > 0; off >>= 1) {
        ssum += __shfl_down(ssum, off, 64);
        sq   += __shfl_down(sq, off, 64);
    }
    int wave = t >> 6, lane = t & 63;
    if (lane == 0) { redS[wave] = ssum; redQ[wave] = sq; }
    __syncthreads();
    if (t == 0) {
        float S = redS[0] + redS[1] + redS[2] + redS[3];
        float Q = redQ[0] + redQ[1] + redQ[2] + redQ[3];
        int m = bm & 63;
        atomicAdd(&stats[384 + m], S);
        atomicAdd(&stats[448 + m], Q);
    }
}

// ---------------------------------------------------------------------------
// K5: per (b,n): z = relu(bn2(att_out)); 3x3 depthwise conv; stats3.
__global__ __launch_bounds__(256) void k5_conv(
    const float* __restrict__ att_out, const float* __restrict__ Wdw,
    const float* __restrict__ g2, const float* __restrict__ b2,
    float* __restrict__ stats, float* __restrict__ v_g)
{
    int bn = blockIdx.x;
    int b = bn >> 5, n = bn & 31;
    int t = threadIdx.x;
    __shared__ __align__(16) float z_s[66 * 130];
    __shared__ float a2_s[64], c2_s[64];
    __shared__ float redS[4], redQ[4];

    if (t < 64) {
        float mean = stats[384 + t] * (1.0f / 32768.0f);
        float var  = stats[448 + t] * (1.0f / 32768.0f) - mean * mean;
        float a = g2[t] * rsqrtf(var + EPS);
        a2_s[t] = a; c2_s[t] = b2[t] - a * mean;
    }
    for (int i = t; i < 66 * 130; i += 256) z_s[i] = 0.f;
    __syncthreads();

    for (int i = t; i < 2048; i += 256) {
        int m = i >> 5, c4 = (i & 31) * 4;
        float4 vv = *(const float4*)(att_out + (((size_t)(b * 64 + m)) * 32 + n) * 128 + c4);
        float a = a2_s[m], c = c2_s[m];
        float* dst = z_s + (m + 1) * 130 + c4 + 1;
        dst[0] = fmaxf(a * vv.x + c, 0.f);
        dst[1] = fmaxf(a * vv.y + c, 0.f);
        dst[2] = fmaxf(a * vv.z + c, 0.f);
        dst[3] = fmaxf(a * vv.w + c, 0.f);
    }
    float w[9];
#pragma unroll
    for (int i = 0; i < 9; i++) w[i] = Wdw[n * 9 + i];
    __syncthreads();

    int tx = t & 31, ty = t >> 5;
    int d0 = tx * 4;
    float ssum = 0.f, sq = 0.f;
#pragma unroll
    for (int rr = 0; rr < 8; rr++) {
        int h = ty * 8 + rr;
        float o0 = 0.f, o1 = 0.f, o2 = 0.f, o3 = 0.f;
#pragma unroll
        for (int dh = 0; dh < 3; dh++) {
            const float* zr = z_s + (h + dh) * 130 + d0;
#pragma unroll
            for (int dw = 0; dw < 3; dw++) {
                float wv = w[dh * 3 + dw];
                o0 += wv * zr[dw + 0];
                o1 += wv * zr[dw + 1];
                o2 += wv * zr[dw + 2];
                o3 += wv * zr[dw + 3];
            }
        }
        *(float4*)(v_g + ((size_t)bn * 64 + h) * 128 + d0) = make_float4(o0, o1, o2, o3);
        ssum += o0 + o1 + o2 + o3;
        sq   += o0 * o0 + o1 * o1 + o2 * o2 + o3 * o3;
    }
#pragma unroll
    for (int off = 32; off > 0; off >>= 1) {
        ssum += __shfl_down(ssum, off, 64);
        sq   += __shfl_down(sq, off, 64);
    }
    int wave = t >> 6, lane = t & 63;
    if (lane == 0) { redS[wave] = ssum; redQ[wave] = sq; }
    __syncthreads();
    if (t == 0) {
        atomicAdd(&stats[512 + n], redS[0] + redS[1] + redS[2] + redS[3]);
        atomicAdd(&stats[544 + n], redQ[0] + redQ[1] + redQ[2] + redQ[3]);
    }
}

// ---------------------------------------------------------------------------
// K6 v2: out[b,n,o,d] = sum_m Wl3[o,m]*relu(bn3(v[b,n,m,d])) + bn_sc(t_sc)
// grid (2, 256): x = o-half of 64, y = (b,n). Same tiling as K1 v2.
__global__ __launch_bounds__(256) void k6_final(
    const float* __restrict__ v_g, const float* __restrict__ t_sc,
    const float* __restrict__ Wl3, const float* __restrict__ g3,
    const float* __restrict__ b3, const float* __restrict__ gsc,
    const float* __restrict__ bsc, const float* __restrict__ stats,
    float* __restrict__ outp)
{
    int oh = blockIdx.x;       // 0/1
    int bn = blockIdx.y;
    int b = bn >> 5, n = bn & 31;
    int t = threadIdx.x;
    __shared__ __align__(16) float z_s[64 * 128];   // [m][d] relu(bn3(v))
    __shared__ __align__(16) float s_wT[64 * 68];   // [m][o_local]

    float mean3 = stats[512 + n] * (1.0f / 65536.0f);
    float var3  = stats[544 + n] * (1.0f / 65536.0f) - mean3 * mean3;
    float a3 = g3[n] * rsqrtf(var3 + EPS);
    float c3 = b3[n] - a3 * mean3;

    const float4* vsrc = (const float4*)(v_g + (size_t)bn * 8192);
    for (int i = t; i < 2048; i += 256) {
        float4 vv = vsrc[i];
        float4 r;
        r.x = fmaxf(a3 * vv.x + c3, 0.f);
        r.y = fmaxf(a3 * vv.y + c3, 0.f);
        r.z = fmaxf(a3 * vv.z + c3, 0.f);
        r.w = fmaxf(a3 * vv.w + c3, 0.f);
        ((float4*)z_s)[i] = r;
    }
    const float* wbase = Wl3 + (size_t)oh * 64 * 64;
    for (int i = t; i < 1024; i += 256) {
        int m = i >> 4, rq = (i & 15) * 4;
        float4 wv;
        wv.x = wbase[(size_t)(rq + 0) * 64 + m];
        wv.y = wbase[(size_t)(rq + 1) * 64 + m];
        wv.z = wbase[(size_t)(rq + 2) * 64 + m];
        wv.w = wbase[(size_t)(rq + 3) * 64 + m];
        *(float4*)(s_wT + m * 68 + rq) = wv;
    }
    __syncthreads();

    int wv = t >> 6, lane = t & 63;
    int dl = lane & 15, g4 = lane >> 4;
    int d0 = dl * 8;
    int c0 = wv * 16 + g4 * 4;

    float4 acc[4][2];
#pragma unroll
    for (int i = 0; i < 4; i++) { acc[i][0] = make_float4(0,0,0,0); acc[i][1] = make_float4(0,0,0,0); }

    for (int m = 0; m < 64; m += 2) {
        float4 x00 = *(const float4*)(z_s + m * 128 + d0);
        float4 x01 = *(const float4*)(z_s + m * 128 + d0 + 4);
        float4 x10 = *(const float4*)(z_s + (m + 1) * 128 + d0);
        float4 x11 = *(const float4*)(z_s + (m + 1) * 128 + d0 + 4);
        float4 w0 = *(const float4*)(s_wT + m * 68 + c0);
        float4 w1 = *(const float4*)(s_wT + (m + 1) * 68 + c0);
        fma4(acc[0][0], w0.x, x00); fma4(acc[0][1], w0.x, x01);
        fma4(acc[1][0], w0.y, x00); fma4(acc[1][1], w0.y, x01);
        fma4(acc[2][0], w0.z, x00); fma4(acc[2][1], w0.z, x01);
        fma4(acc[3][0], w0.w, x00); fma4(acc[3][1], w0.w, x01);
        fma4(acc[0][0], w1.x, x10); fma4(acc[0][1], w1.x, x11);
        fma4(acc[1][0], w1.y, x10); fma4(acc[1][1], w1.y, x11);
        fma4(acc[2][0], w1.z, x10); fma4(acc[2][1], w1.z, x11);
        fma4(acc[3][0], w1.w, x10); fma4(acc[3][1], w1.w, x11);
    }

#pragma unroll
    for (int i = 0; i < 4; i++) {
        int o = oh * 64 + c0 + i;
        float msc = stats[o] * (1.0f / 32768.0f);
        float vsc = stats[128 + o] * (1.0f / 32768.0f) - msc * msc;
        float asc = gsc[o] * rsqrtf(vsc + EPS);
        float csc = bsc[o] - asc * msc;
        const float* ts = t_sc + (((size_t)(b * 128 + o)) * 32 + n) * 128 + d0;
        float4 t0 = *(const float4*)(ts);
        float4 t1 = *(const float4*)(ts + 4);
        float4 o0 = acc[i][0], o1 = acc[i][1];
        o0.x += asc * t0.x + csc; o0.y += asc * t0.y + csc;
        o0.z += asc * t0.z + csc; o0.w += asc * t0.w + csc;
        o1.x += asc * t1.x + csc; o1.y += asc * t1.y + csc;
        o1.z += asc * t1.z + csc; o1.w += asc * t1.w + csc;
        float* dst = outp + (((size_t)(b * 32 + n)) * 128 + o) * 128 + d0;
        *(float4*)dst = o0;
        *(float4*)(dst + 4) = o1;
    }
}

// ---------------------------------------------------------------------------
extern "C" void kernel_launch(void* const* d_in, const int* in_sizes, int n_in,
                              void* d_out, int out_size, void* d_ws, size_t ws_size,
                              hipStream_t stream)
{
    const float* x    = (const float*)d_in[0];
    const float* Wsc  = (const float*)d_in[1];
    const float* gsc  = (const float*)d_in[2];
    const float* bsc  = (const float*)d_in[3];
    const float* Wl1  = (const float*)d_in[4];
    const float* g1   = (const float*)d_in[5];
    const float* b1   = (const float*)d_in[6];
    const float* Wfc1 = (const float*)d_in[7];
    const float* Wfc2 = (const float*)d_in[8];
    const float* g2   = (const float*)d_in[9];
    const float* b2   = (const float*)d_in[10];
    const float* Wdw  = (const float*)d_in[11];
    const float* g3   = (const float*)d_in[12];
    const float* b3   = (const float*)d_in[13];
    const float* Wl3  = (const float*)d_in[14];
    float* outp = (float*)d_out;

    float* ws = (float*)d_ws;
    float* stats = ws;                          // 1024
    float* t_sc  = ws + 1024;                   // 4194304
    float* t_l1  = t_sc + 4194304;              // 2097152 (reused as att_out)
    float* y_g   = t_l1 + 2097152;              // 2097152 (reused as conv out)
    float* E     = y_g + 2097152;               // 524288
    float* H     = E + 524288;                  // 262144
    float* E2    = H + 262144;                  // 524288
    unsigned int* maskb = (unsigned int*)(E2 + 524288);  // 16384 u32

    (void)hipMemsetAsync(stats, 0, 1024 * sizeof(float), stream);

    k1_matmul_stats<<<dim3(3, 256), 256, 0, stream>>>(x, Wsc, Wl1, t_sc, t_l1, stats);
    k2_attn_prep<<<512, 256, 0, stream>>>(t_l1, g1, b1, stats, y_g, E, maskb);
    k3_gemm<1024, 0><<<dim3(16, 16), 256, 0, stream>>>(E, Wfc1, H, 512);
    k3_gemm<512, 1><<<dim3(32, 16), 256, 0, stream>>>(H, Wfc2, E2, 1024);
    k4_attn_apply<<<512, 256, 0, stream>>>(E2, maskb, y_g, t_l1, stats);
    k5_conv<<<256, 256, 0, stream>>>(t_l1, Wdw, g2, b2, stats, y_g);
    k6_final<<<dim3(2, 256), 256, 0, stream>>>(y_g, t_sc, Wl3, g3, b3, gsc, bsc, stats, outp);
}